// Round 8
// baseline (371.786 us; speedup 1.0000x reference)
//
#include <hip/hip_runtime.h>
#include <hip/hip_bf16.h>
#include <stdint.h>

// out[b,l,i,o] = sum_d head[b,i,d]*U[l,d]*dep[b,o,d] + t2h[b,l,i] + t2d[b,l,o] + b[l]
// B=16, S=256, D=768, L=32. out (16,32,256,256) fp32.
//
// R10: barrier-free, LDS-free main K-loop. 8 waves/block (512 thr), block
// tile 128x256, wave tile 64x64 (acc=64 VGPR), grid 1024. Each wave loads
// its MFMA A-fragments DIRECT from head (2 float4/rt), scales by U and packs
// in registers (af double-buffered), B frags direct from fragment-major depb
// (bf double-buffered). All loads one iter ahead with counted vmcnt; no
// s_barrier in the loop (only one __syncthreads after T2 stage). Accumulation
// order bit-identical to R5/R6. prep unchanged from R6.

#define B_ 16
#define S_ 256
#define D_ 768
#define L_ 32
#define KQ_ (D_ / 8)  // 96 groups of 8 d's
#define NT_ 24        // K-tiles of 32

typedef unsigned short ushort_t;
typedef __attribute__((ext_vector_type(4))) float f32x4;
typedef __attribute__((ext_vector_type(8))) short s16x8;

// round-half-up fp32->bf16 pair pack; f0 -> low half, f1 -> high half
__device__ __forceinline__ unsigned int pack_bf16(float f0, float f1) {
  unsigned int u0 = __builtin_bit_cast(unsigned int, f0) + 0x8000u;
  unsigned int u1 = __builtin_bit_cast(unsigned int, f1) + 0x8000u;
  return __builtin_amdgcn_perm(u1, u0, 0x07060302);
}

// ---------------------------------------------------------------------------
// Prep: one wave per 4 rows. Lane owns 12 d's in registers. t2 dots: per-lane
// FMA partials for 16 labels x 4 rows, then ONE packed transpose-butterfly
// (63 shuffles) delivers output j = l*4 + r to lane j. Two label-chunks.
// dep waves also emit bf16 depb in fragment-major layout
// depb[b][d>>3][col][d&7]. grid = 512 x 256 = 2048 waves = B*S*2/4 rows.
// ---------------------------------------------------------------------------
__global__ __launch_bounds__(256) void prep_kernel(
    const float* __restrict__ head, const float* __restrict__ dep,
    const float* __restrict__ labelW, ushort_t* __restrict__ depb,
    float* __restrict__ t2h, float* __restrict__ t2d) {
  const int wave = threadIdx.x >> 6;
  const int lane = threadIdx.x & 63;
  const int g = blockIdx.x * 4 + wave;  // 0..2047
  const int sel = g >> 10;              // 0=head, 1=dep
  const int idx = g & 1023;
  const int b = idx >> 6;
  const int row0 = (idx & 63) * 4;
  const float* src = sel ? dep : head;
  float* t2x = sel ? t2d : t2h;
  const int d0 = lane * 12;

  float h[4][12];
  const float* rp = src + ((size_t)(b * S_ + row0)) * D_ + d0;
#pragma unroll
  for (int r = 0; r < 4; ++r) {
    float4 v0 = *(const float4*)(rp + (size_t)r * D_);
    float4 v1 = *(const float4*)(rp + (size_t)r * D_ + 4);
    float4 v2 = *(const float4*)(rp + (size_t)r * D_ + 8);
    h[r][0] = v0.x; h[r][1] = v0.y; h[r][2] = v0.z; h[r][3] = v0.w;
    h[r][4] = v1.x; h[r][5] = v1.y; h[r][6] = v1.z; h[r][7] = v1.w;
    h[r][8] = v2.x; h[r][9] = v2.y; h[r][10] = v2.z; h[r][11] = v2.w;
  }
  if (sel) {
    // fragment-major: ushort off = ((b*96 + (d>>3))*256 + col)*8 + (d&7)
    const size_t bb = (size_t)b * (KQ_ * S_ * 8);
    const int m = lane >> 1;  // d0 = 24m (even lane) or 24m+12 (odd lane)
#pragma unroll
    for (int r = 0; r < 4; ++r) {
      const int col = row0 + r;
      unsigned int q0 = pack_bf16(h[r][0], h[r][1]);
      unsigned int q1 = pack_bf16(h[r][2], h[r][3]);
      unsigned int q2 = pack_bf16(h[r][4], h[r][5]);
      unsigned int q3 = pack_bf16(h[r][6], h[r][7]);
      unsigned int q4 = pack_bf16(h[r][8], h[r][9]);
      unsigned int q5 = pack_bf16(h[r][10], h[r][11]);
      if ((lane & 1) == 0) {
        uint4 a = {q0, q1, q2, q3};  // d0..d7 @ kq=3m
        uint2 c = {q4, q5};          // d8..d11 @ kq=3m+1, dlow 0..3
        *(uint4*)(depb + bb + ((size_t)(3 * m) * S_ + col) * 8) = a;
        *(uint2*)(depb + bb + ((size_t)(3 * m + 1) * S_ + col) * 8) = c;
      } else {
        uint2 c = {q0, q1};          // d0..d3 @ kq=3m+1, dlow 4..7
        uint4 a = {q2, q3, q4, q5};  // d4..d11 @ kq=3m+2
        *(uint2*)(depb + bb + ((size_t)(3 * m + 1) * S_ + col) * 8 + 4) = c;
        *(uint4*)(depb + bb + ((size_t)(3 * m + 2) * S_ + col) * 8) = a;
      }
    }
  }
  const float* wbase = labelW + sel * D_ + d0;
  // two chunks of 16 labels; v[j] = partial for output j = lq*4 + r
  for (int c = 0; c < 2; ++c) {
    float v[64];
#pragma unroll
    for (int j = 0; j < 64; ++j) v[j] = 0.f;
    const float* wc = wbase + (size_t)(c * 16) * (2 * D_);
#pragma unroll
    for (int lq = 0; lq < 16; ++lq) {
      const float* wp = wc + (size_t)lq * (2 * D_);
      float4 w0 = *(const float4*)(wp);
      float4 w1 = *(const float4*)(wp + 4);
      float4 w2 = *(const float4*)(wp + 8);
      float w[12] = {w0.x, w0.y, w0.z, w0.w, w1.x, w1.y, w1.z, w1.w,
                     w2.x, w2.y, w2.z, w2.w};
#pragma unroll
      for (int j = 0; j < 12; ++j) {
        v[lq * 4 + 0] += h[0][j] * w[j];
        v[lq * 4 + 1] += h[1][j] * w[j];
        v[lq * 4 + 2] += h[2][j] * w[j];
        v[lq * 4 + 3] += h[3][j] * w[j];
      }
    }
    // packed transpose-butterfly: combine order (own + partner, high bit
    // first) matches the old per-output allreduce bit-for-bit.
#pragma unroll
    for (int off = 32; off >= 1; off >>= 1) {
      const bool hi = (lane & off) != 0;
#pragma unroll
      for (int k = 0; k < 64; ++k) {
        if (k >= off) continue;  // live window is [0, off)
        float send = hi ? v[k] : v[k + off];
        float keep = hi ? v[k + off] : v[k];
        v[k] = keep + __shfl_xor(send, off);
      }
    }
    t2x[((size_t)(b * L_ + c * 16 + (lane >> 2))) * S_ + row0 + (lane & 3)] =
        v[0];
  }
}

// ---------------------------------------------------------------------------
// Main: block = (b, l, i-half). Tile 128(i) x 256(o), 8 waves of 64x64
// (2 row-halves x 4 col-groups). grid = B*L*2 = 1024 blocks, 512 threads.
// No LDS (except T2), no barriers in the K-loop.
// ---------------------------------------------------------------------------

// build one A-frag (s16x8): k kg*8..+7 of one row, scaled by U and packed
#define PACK1(DST, ha, hb, uu0, uu1)                                          \
  {                                                                           \
    uint4 w;                                                                  \
    w.x = pack_bf16((ha).x * (uu0).x, (ha).y * (uu0).y);                      \
    w.y = pack_bf16((ha).z * (uu0).z, (ha).w * (uu0).w);                      \
    w.z = pack_bf16((hb).x * (uu1).x, (hb).y * (uu1).y);                      \
    w.w = pack_bf16((hb).z * (uu1).z, (hb).w * (uu1).w);                      \
    DST = __builtin_bit_cast(s16x8, w);                                       \
  }

__global__ __launch_bounds__(512, 2) void main_kernel(
    const float* __restrict__ head, const ushort_t* __restrict__ depb,
    const float* __restrict__ U, const float* __restrict__ bias,
    const float* __restrict__ t2h, const float* __restrict__ t2d,
    float* __restrict__ out) {
  __shared__ float T2[384];  // [0:128]=t2h tile rows, [128:384]=t2d all cols

  // XCD-bijective swizzle: grid 1024 = 8 XCDs x 128 contiguous blocks (2 b's)
  const int hw = blockIdx.x;
  const int bid = ((hw & 7) << 7) | (hw >> 3);
  const int ic = bid & 1;
  const int bl = bid >> 1;
  const int l = bl & (L_ - 1);
  const int b = bl >> 5;
  const int ti = ic * 128;
  const int t = threadIdx.x;
  const int lane = t & 63;
  const int wave = t >> 6;
  const int rh = wave >> 2;  // row half: rows rh*64..+64
  const int cg = wave & 3;   // col group: cols cg*64..+64

  for (int i = t; i < 384; i += 512)
    T2[i] = (i < 128) ? t2h[((size_t)(b * L_ + l)) * S_ + ti + i]
                      : t2d[((size_t)(b * L_ + l)) * S_ + (i - 128)];
  __syncthreads();  // the only block-wide barrier
  const float bv = bias[l];

  const int colg = lane & 15;  // A row / B col within 16
  const int kg = lane >> 4;    // k-group within 32-k step

  // A-frag direct pointer: row = ti + rh*64 + rt*16 + colg, k = kg*8 + kk
  const float* hf =
      head + ((size_t)(b * S_ + ti + rh * 64 + colg)) * D_ + kg * 8;
  const float* Up = U + (size_t)l * D_ + kg * 8;
  // B-frag: col = cg*64 + ct*16 + colg, depb[b][kq][col][8]
  const ushort_t* dfb = depb + (size_t)b * (KQ_ * S_ * 8) +
                        ((size_t)(kg * 256 + cg * 64 + colg)) * 8;

  f32x4 acc[4][4];
#pragma unroll
  for (int i = 0; i < 4; ++i)
#pragma unroll
    for (int j = 0; j < 4; ++j) acc[i][j] = {0.f, 0.f, 0.f, 0.f};

  s16x8 afA[4], afB[4], bfA[4], bfB[4];

  // prologue: load+pack af(0) -> afA; load bf(0) -> bfA
  {
    float4 u0 = *(const float4*)(Up);
    float4 u1 = *(const float4*)(Up + 4);
    float4 h00 = *(const float4*)(hf);
    float4 h01 = *(const float4*)(hf + 4);
    float4 h10 = *(const float4*)(hf + 12288);   // +16 rows
    float4 h11 = *(const float4*)(hf + 12292);
    float4 h20 = *(const float4*)(hf + 24576);   // +32 rows
    float4 h21 = *(const float4*)(hf + 24580);
    float4 h30 = *(const float4*)(hf + 36864);   // +48 rows
    float4 h31 = *(const float4*)(hf + 36868);
#pragma unroll
    for (int ct = 0; ct < 4; ++ct)
      bfA[ct] = *(const s16x8*)(dfb + ct * 128);
    PACK1(afA[0], h00, h01, u0, u1)
    PACK1(afA[1], h10, h11, u0, u1)
    PACK1(afA[2], h20, h21, u0, u1)
    PACK1(afA[3], h30, h31, u0, u1)
  }

  // Per iteration (tile tcur): issue head/U(t+1) then B(t+1) (counted vmcnt
  // keeps B in flight across the pack's wait), 16 MFMA on current frags,
  // pack af(t+1) under the MFMAs. No barriers, no LDS.
#define ITER(AFC, AFN, BFC, BFN, tcur)                                        \
  {                                                                           \
    int tn = (tcur) + 1;                                                      \
    if (tn == NT_) tn = 0; /* wrapped dummy prefetch keeps code uniform */    \
    const float* hq = hf + tn * 32;                                           \
    float4 u0 = *(const float4*)(Up + tn * 32);                               \
    float4 u1 = *(const float4*)(Up + tn * 32 + 4);                           \
    float4 h00 = *(const float4*)(hq);                                        \
    float4 h01 = *(const float4*)(hq + 4);                                    \
    float4 h10 = *(const float4*)(hq + 12288);                                \
    float4 h11 = *(const float4*)(hq + 12292);                                \
    float4 h20 = *(const float4*)(hq + 24576);                                \
    float4 h21 = *(const float4*)(hq + 24580);                                \
    float4 h30 = *(const float4*)(hq + 36864);                                \
    float4 h31 = *(const float4*)(hq + 36868);                                \
    const ushort_t* dfn = dfb + (size_t)tn * 8192;                            \
    _Pragma("unroll") for (int ct = 0; ct < 4; ++ct)                          \
        BFN[ct] = *(const s16x8*)(dfn + ct * 128);                            \
    __builtin_amdgcn_sched_barrier(0); /* pin load-issue cluster here */      \
    _Pragma("unroll") for (int rt = 0; rt < 4; ++rt)                          \
      _Pragma("unroll") for (int ct = 0; ct < 4; ++ct)                        \
          acc[rt][ct] = __builtin_amdgcn_mfma_f32_16x16x32_bf16(              \
              AFC[rt], BFC[ct], acc[rt][ct], 0, 0, 0);                        \
    PACK1(AFN[0], h00, h01, u0, u1)                                           \
    PACK1(AFN[1], h10, h11, u0, u1)                                           \
    PACK1(AFN[2], h20, h21, u0, u1)                                           \
    PACK1(AFN[3], h30, h31, u0, u1)                                           \
  }

  for (int tt = 0; tt < NT_; tt += 2) {
    ITER(afA, afB, bfA, bfB, tt)
    ITER(afB, afA, bfB, bfA, tt + 1)
  }
#undef ITER

  // epilogue: C/D layout col=lane&15, row=(lane>>4)*4+reg
  const int rgrp = lane >> 4;
  float* ob =
      out + (((size_t)(b * L_ + l)) * S_ + ti + rh * 64) * S_ + cg * 64;
#pragma unroll
  for (int rt = 0; rt < 4; ++rt) {
    const int r0 = rt * 16 + rgrp * 4;
#pragma unroll
    for (int ct = 0; ct < 4; ++ct) {
      const int c = ct * 16 + colg;
      const float addc = T2[128 + cg * 64 + c] + bv;
      float* p = ob + (size_t)r0 * S_ + c;
#pragma unroll
      for (int r = 0; r < 4; ++r)
        p[(size_t)r * S_] = acc[rt][ct][r] + T2[rh * 64 + r0 + r] + addc;
    }
  }
}

extern "C" void kernel_launch(void* const* d_in, const int* in_sizes, int n_in,
                              void* d_out, int out_size, void* d_ws, size_t ws_size,
                              hipStream_t stream) {
  const float* head = (const float*)d_in[0];
  const float* dep = (const float*)d_in[1];
  const float* U = (const float*)d_in[2];
  const float* W = (const float*)d_in[3];
  const float* bias = (const float*)d_in[4];
  float* out = (float*)d_out;

  ushort_t* depb = (ushort_t*)d_ws;                              // 6,291,456 B
  float* t2h = (float*)((char*)d_ws + (size_t)B_ * S_ * D_ * 2);
  float* t2d = t2h + (size_t)B_ * L_ * S_;                       // 524,288 B each

  prep_kernel<<<512, 256, 0, stream>>>(head, dep, W, depb, t2h, t2d);
  main_kernel<<<B_ * L_ * 2, 512, 0, stream>>>(head, depb, U, bias, t2h, t2d, out);
}

// Round 9
// 214.505 us; speedup vs baseline: 1.7332x; 1.7332x over previous
//
#include <hip/hip_runtime.h>
#include <hip/hip_bf16.h>
#include <stdint.h>

// out[b,l,i,o] = sum_d head[b,i,d]*U[l,d]*dep[b,o,d] + t2h[b,l,i] + t2d[b,l,o] + b[l]
// B=16, S=256, D=768, L=32. out (16,32,256,256) fp32.
//
// R11: R5 geometry (grid 1024, 256 thr, 4 waves of 128x64, swizzled A-LDS,
// B direct-to-register) with K-step 64 = two phase-local 32-k phases per
// barrier-iter: 12 lgkm-only barriers per block (was 24). Per phase:
// prefetch next 32-k B chunk (ping-pong regs), issue h/u staging chunk,
// 8 af ds_reads, 32 MFMA (setprio), pack+ds_write. Phase 1's ds_reads
// overlap phase 0's MFMAs (same completed buffer). Accumulation order
// bit-identical to R5/R6. prep unchanged from R6.

#define B_ 16
#define S_ 256
#define D_ 768
#define L_ 32
#define KQ_ (D_ / 8)  // 96 groups of 8 d's
#define NT_ 12        // barrier-iters of 64 k
#define NC_ 24        // 32-k chunks total

typedef unsigned short ushort_t;
typedef __attribute__((ext_vector_type(4))) float f32x4;
typedef __attribute__((ext_vector_type(8))) short s16x8;

// round-half-up fp32->bf16 pair pack; f0 -> low half, f1 -> high half
__device__ __forceinline__ unsigned int pack_bf16(float f0, float f1) {
  unsigned int u0 = __builtin_bit_cast(unsigned int, f0) + 0x8000u;
  unsigned int u1 = __builtin_bit_cast(unsigned int, f1) + 0x8000u;
  return __builtin_amdgcn_perm(u1, u0, 0x07060302);
}

// ---------------------------------------------------------------------------
// Prep: one wave per 4 rows. Lane owns 12 d's in registers. t2 dots: per-lane
// FMA partials for 16 labels x 4 rows, then ONE packed transpose-butterfly
// (63 shuffles) delivers output j = l*4 + r to lane j. Two label-chunks.
// dep waves also emit bf16 depb in fragment-major layout
// depb[b][d>>3][col][d&7]. grid = 512 x 256 = 2048 waves = B*S*2/4 rows.
// ---------------------------------------------------------------------------
__global__ __launch_bounds__(256) void prep_kernel(
    const float* __restrict__ head, const float* __restrict__ dep,
    const float* __restrict__ labelW, ushort_t* __restrict__ depb,
    float* __restrict__ t2h, float* __restrict__ t2d) {
  const int wave = threadIdx.x >> 6;
  const int lane = threadIdx.x & 63;
  const int g = blockIdx.x * 4 + wave;  // 0..2047
  const int sel = g >> 10;              // 0=head, 1=dep
  const int idx = g & 1023;
  const int b = idx >> 6;
  const int row0 = (idx & 63) * 4;
  const float* src = sel ? dep : head;
  float* t2x = sel ? t2d : t2h;
  const int d0 = lane * 12;

  float h[4][12];
  const float* rp = src + ((size_t)(b * S_ + row0)) * D_ + d0;
#pragma unroll
  for (int r = 0; r < 4; ++r) {
    float4 v0 = *(const float4*)(rp + (size_t)r * D_);
    float4 v1 = *(const float4*)(rp + (size_t)r * D_ + 4);
    float4 v2 = *(const float4*)(rp + (size_t)r * D_ + 8);
    h[r][0] = v0.x; h[r][1] = v0.y; h[r][2] = v0.z; h[r][3] = v0.w;
    h[r][4] = v1.x; h[r][5] = v1.y; h[r][6] = v1.z; h[r][7] = v1.w;
    h[r][8] = v2.x; h[r][9] = v2.y; h[r][10] = v2.z; h[r][11] = v2.w;
  }
  if (sel) {
    // fragment-major: ushort off = ((b*96 + (d>>3))*256 + col)*8 + (d&7)
    const size_t bb = (size_t)b * (KQ_ * S_ * 8);
    const int m = lane >> 1;  // d0 = 24m (even lane) or 24m+12 (odd lane)
#pragma unroll
    for (int r = 0; r < 4; ++r) {
      const int col = row0 + r;
      unsigned int q0 = pack_bf16(h[r][0], h[r][1]);
      unsigned int q1 = pack_bf16(h[r][2], h[r][3]);
      unsigned int q2 = pack_bf16(h[r][4], h[r][5]);
      unsigned int q3 = pack_bf16(h[r][6], h[r][7]);
      unsigned int q4 = pack_bf16(h[r][8], h[r][9]);
      unsigned int q5 = pack_bf16(h[r][10], h[r][11]);
      if ((lane & 1) == 0) {
        uint4 a = {q0, q1, q2, q3};  // d0..d7 @ kq=3m
        uint2 c = {q4, q5};          // d8..d11 @ kq=3m+1, dlow 0..3
        *(uint4*)(depb + bb + ((size_t)(3 * m) * S_ + col) * 8) = a;
        *(uint2*)(depb + bb + ((size_t)(3 * m + 1) * S_ + col) * 8) = c;
      } else {
        uint2 c = {q0, q1};          // d0..d3 @ kq=3m+1, dlow 4..7
        uint4 a = {q2, q3, q4, q5};  // d4..d11 @ kq=3m+2
        *(uint2*)(depb + bb + ((size_t)(3 * m + 1) * S_ + col) * 8 + 4) = c;
        *(uint4*)(depb + bb + ((size_t)(3 * m + 2) * S_ + col) * 8) = a;
      }
    }
  }
  const float* wbase = labelW + sel * D_ + d0;
  // two chunks of 16 labels; v[j] = partial for output j = lq*4 + r
  for (int c = 0; c < 2; ++c) {
    float v[64];
#pragma unroll
    for (int j = 0; j < 64; ++j) v[j] = 0.f;
    const float* wc = wbase + (size_t)(c * 16) * (2 * D_);
#pragma unroll
    for (int lq = 0; lq < 16; ++lq) {
      const float* wp = wc + (size_t)lq * (2 * D_);
      float4 w0 = *(const float4*)(wp);
      float4 w1 = *(const float4*)(wp + 4);
      float4 w2 = *(const float4*)(wp + 8);
      float w[12] = {w0.x, w0.y, w0.z, w0.w, w1.x, w1.y, w1.z, w1.w,
                     w2.x, w2.y, w2.z, w2.w};
#pragma unroll
      for (int j = 0; j < 12; ++j) {
        v[lq * 4 + 0] += h[0][j] * w[j];
        v[lq * 4 + 1] += h[1][j] * w[j];
        v[lq * 4 + 2] += h[2][j] * w[j];
        v[lq * 4 + 3] += h[3][j] * w[j];
      }
    }
    // packed transpose-butterfly: combine order (own + partner, high bit
    // first) matches the old per-output allreduce bit-for-bit.
#pragma unroll
    for (int off = 32; off >= 1; off >>= 1) {
      const bool hi = (lane & off) != 0;
#pragma unroll
      for (int k = 0; k < 64; ++k) {
        if (k >= off) continue;  // live window is [0, off)
        float send = hi ? v[k] : v[k + off];
        float keep = hi ? v[k + off] : v[k];
        v[k] = keep + __shfl_xor(send, off);
      }
    }
    t2x[((size_t)(b * L_ + c * 16 + (lane >> 2))) * S_ + row0 + (lane & 3)] =
        v[0];
  }
}

// ---------------------------------------------------------------------------
// Main: block = (b, l, i-half). Tile 128(i) x 256(o), 4 waves of 128x64.
// grid = B*L*2 = 1024 blocks, 256 threads.
// ---------------------------------------------------------------------------

// XOR-swizzle on ushort offsets within a 4KB phase sub-buffer: kgrp (bits
// 11:10) into bits 5:4. Bijective; both A ds_write and ds_read uniform 2/bank.
#define SWZ(o) ((o) ^ ((((o) >> 10) & 3) << 4))

__global__ __launch_bounds__(256, 2) void main_kernel(
    const float* __restrict__ head, const ushort_t* __restrict__ depb,
    const float* __restrict__ U, const float* __restrict__ bias,
    const float* __restrict__ t2h, const float* __restrict__ t2d,
    float* __restrict__ out) {
  // A: [buf(2)][phase(2)][kgrp(4)][row(128)][8] bf16, XOR-swizzled per phase
  __shared__ __attribute__((aligned(16))) ushort_t As[2 * 2 * 4096];  // 32 KB
  __shared__ float T2[384];  // [0:128]=t2h tile rows, [128:384]=t2d all cols

  // XCD-bijective swizzle: grid 1024 = 8 XCDs x 128 contiguous blocks (2 b's)
  const int hw = blockIdx.x;
  const int bid = ((hw & 7) << 7) | (hw >> 3);
  const int ic = bid & 1;
  const int bl = bid >> 1;
  const int l = bl & (L_ - 1);
  const int b = bl >> 5;
  const int ti = ic * 128;
  const int t = threadIdx.x;
  const int lane = t & 63;
  const int wave = t >> 6;

  for (int i = t; i < 384; i += 256)
    T2[i] = (i < 128) ? t2h[((size_t)(b * L_ + l)) * S_ + ti + i]
                      : t2d[((size_t)(b * L_ + l)) * S_ + (i - 128)];
  const float bv = bias[l];

  // A staging decomposition: thread t stages rows (t>>2, t>>2+64), kgrp t&3
  const int row0 = t >> 2;
  const int kg = t & 3;
  const float* hp0 = head + ((size_t)(b * S_ + ti + row0)) * D_ + kg * 8;
  const float* hp1 = hp0 + (size_t)64 * D_;
  const float* Up = U + (size_t)l * D_ + kg * 8;
  const int awo0s = SWZ((kg * 128 + row0) * 8);
  const int awo1s = awo0s + 512;  // +64 rows; doesn't touch swizzled bits

  // A frag reads: rows rt*16+(lane&15), kgrp=lane>>4 (wave reads all 128 rows)
  const int aros = SWZ(((lane >> 4) * 128 + (lane & 15)) * 8);

  // B direct-from-global: wave owns cols [wave*64, wave*64+64)
  const ushort_t* dfb = depb + (size_t)b * (KQ_ * S_ * 8) +
                        ((size_t)((lane >> 4) * 256 + wave * 64 + (lane & 15))) * 8;

  f32x4 acc[8][4];
#pragma unroll
  for (int i = 0; i < 8; ++i)
#pragma unroll
    for (int j = 0; j < 4; ++j) acc[i][j] = {0.f, 0.f, 0.f, 0.f};

  s16x8 bfA[4], bfB[4];

#define LOAD_HU(ku)                                                           \
    float4 h0 = *(const float4*)(hp0 + (ku) * 32);                            \
    float4 h1 = *(const float4*)(hp0 + (ku) * 32 + 4);                        \
    float4 h2 = *(const float4*)(hp1 + (ku) * 32);                            \
    float4 h3 = *(const float4*)(hp1 + (ku) * 32 + 4);                        \
    float4 u0 = *(const float4*)(Up + (ku) * 32);                             \
    float4 u1 = *(const float4*)(Up + (ku) * 32 + 4);

#define PACK_WRITE_A(DST)                                                     \
  {                                                                           \
    uint4 w0, w1;                                                             \
    w0.x = pack_bf16(h0.x * u0.x, h0.y * u0.y);                               \
    w0.y = pack_bf16(h0.z * u0.z, h0.w * u0.w);                               \
    w0.z = pack_bf16(h1.x * u1.x, h1.y * u1.y);                               \
    w0.w = pack_bf16(h1.z * u1.z, h1.w * u1.w);                               \
    w1.x = pack_bf16(h2.x * u0.x, h2.y * u0.y);                               \
    w1.y = pack_bf16(h2.z * u0.z, h2.w * u0.w);                               \
    w1.z = pack_bf16(h3.x * u1.x, h3.y * u1.y);                               \
    w1.w = pack_bf16(h3.z * u1.z, h3.w * u1.w);                               \
    *(uint4*)((DST) + awo0s) = w0;                                            \
    *(uint4*)((DST) + awo1s) = w1;                                            \
  }

  // prologue: stage chunks 0,1 into As[0][0..1]; load bfA <- B chunk 0
  {
    {
      LOAD_HU(0)
      PACK_WRITE_A(As)
    }
    {
      LOAD_HU(1)
      PACK_WRITE_A(As + 4096)
    }
#pragma unroll
    for (int ct = 0; ct < 4; ++ct)
      bfA[ct] = *(const s16x8*)(dfb + ct * 128);
  }
  asm volatile("s_waitcnt lgkmcnt(0)" ::: "memory");
  __builtin_amdgcn_s_barrier();
  __builtin_amdgcn_sched_barrier(0);

  // Barrier-iter tt (chunks 2tt, 2tt+1 from As[cur]): phase 0 consumes bfA +
  // As[cur][0], prefetches B chunk 2tt+1 -> bfB and stages chunk 2tt+2 ->
  // As[cur^1][0]; phase 1 consumes bfB + As[cur][1], prefetches B 2tt+2 ->
  // bfA and stages 2tt+3 -> As[cur^1][1]. One lgkm drain + barrier per iter.
  int cur = 0;
  for (int tt = 0; tt < NT_; ++tt) {
    const ushort_t* pr = As + cur * 8192;         // read buffer
    ushort_t* pw = As + (cur ^ 1) * 8192;         // write buffer
    // ---- phase 0 ----
    {
      int cb = 2 * tt + 1;                        // B chunk for phase 1
      const ushort_t* dfn = dfb + (size_t)cb * 8192;
#pragma unroll
      for (int ct = 0; ct < 4; ++ct)
        bfB[ct] = *(const s16x8*)(dfn + ct * 128);
      int ks = 2 * tt + 2;                        // staging chunk
      if (ks >= NC_) ks -= NC_;                   // wrapped dummy on last iter
      LOAD_HU(ks)
      __builtin_amdgcn_sched_barrier(0);          // pin load-issue cluster
      s16x8 af[8];
#pragma unroll
      for (int rt = 0; rt < 8; ++rt)
        af[rt] = *(const s16x8*)(pr + aros + rt * 128);
      __builtin_amdgcn_s_setprio(1);
#pragma unroll
      for (int rt = 0; rt < 8; ++rt)
#pragma unroll
        for (int ct = 0; ct < 4; ++ct)
          acc[rt][ct] = __builtin_amdgcn_mfma_f32_16x16x32_bf16(
              af[rt], bfA[ct], acc[rt][ct], 0, 0, 0);
      __builtin_amdgcn_s_setprio(0);
      PACK_WRITE_A(pw)
    }
    // ---- phase 1 ----
    {
      int cb = 2 * tt + 2;                        // B chunk for next iter
      if (cb >= NC_) cb -= NC_;                   // wrapped dummy on last iter
      const ushort_t* dfn = dfb + (size_t)cb * 8192;
#pragma unroll
      for (int ct = 0; ct < 4; ++ct)
        bfA[ct] = *(const s16x8*)(dfn + ct * 128);
      int ks = 2 * tt + 3;                        // staging chunk
      if (ks >= NC_) ks -= NC_;
      LOAD_HU(ks)
      __builtin_amdgcn_sched_barrier(0);          // pin load-issue cluster
      s16x8 af[8];
#pragma unroll
      for (int rt = 0; rt < 8; ++rt)
        af[rt] = *(const s16x8*)(pr + 4096 + aros + rt * 128);
      __builtin_amdgcn_s_setprio(1);
#pragma unroll
      for (int rt = 0; rt < 8; ++rt)
#pragma unroll
        for (int ct = 0; ct < 4; ++ct)
          acc[rt][ct] = __builtin_amdgcn_mfma_f32_16x16x32_bf16(
              af[rt], bfB[ct], acc[rt][ct], 0, 0, 0);
      __builtin_amdgcn_s_setprio(0);
      PACK_WRITE_A(pw + 4096)
    }
    asm volatile("s_waitcnt lgkmcnt(0)" ::: "memory");
    __builtin_amdgcn_s_barrier();
    __builtin_amdgcn_sched_barrier(0);
    cur ^= 1;
  }
#undef LOAD_HU
#undef PACK_WRITE_A

  // epilogue: C/D layout col=lane&15, row=(lane>>4)*4+reg
  const int colg = lane & 15;
  const int rgrp = lane >> 4;
  float* ob = out + (((size_t)(b * L_ + l)) * S_ + ti) * S_;
#pragma unroll
  for (int rt = 0; rt < 8; ++rt) {
    const int r0 = rt * 16 + rgrp * 4;
#pragma unroll
    for (int ct = 0; ct < 4; ++ct) {
      const int c = wave * 64 + ct * 16 + colg;
      const float addc = T2[128 + c] + bv;
      float* p = ob + (size_t)r0 * S_ + c;
#pragma unroll
      for (int r = 0; r < 4; ++r)
        p[(size_t)r * S_] = acc[rt][ct][r] + T2[r0 + r] + addc;
    }
  }
}

extern "C" void kernel_launch(void* const* d_in, const int* in_sizes, int n_in,
                              void* d_out, int out_size, void* d_ws, size_t ws_size,
                              hipStream_t stream) {
  const float* head = (const float*)d_in[0];
  const float* dep = (const float*)d_in[1];
  const float* U = (const float*)d_in[2];
  const float* W = (const float*)d_in[3];
  const float* bias = (const float*)d_in[4];
  float* out = (float*)d_out;

  ushort_t* depb = (ushort_t*)d_ws;                              // 6,291,456 B
  float* t2h = (float*)((char*)d_ws + (size_t)B_ * S_ * D_ * 2);
  float* t2d = t2h + (size_t)B_ * L_ * S_;                       // 524,288 B each

  prep_kernel<<<512, 256, 0, stream>>>(head, dep, W, depb, t2h, t2d);
  main_kernel<<<B_ * L_ * 2, 256, 0, stream>>>(head, depb, U, bias, t2h, t2d, out);
}